// Round 8
// baseline (202.198 us; speedup 1.0000x reference)
//
#include <hip/hip_runtime.h>
#include <math.h>

#define HW2048 (2048ull*2048ull)
typedef float f4 __attribute__((ext_vector_type(4)));
typedef float f2 __attribute__((ext_vector_type(2)));

struct BP {
  float P[4][3];   // composed 2-stage bilinear phase weights
  float D2[5];     // d^2 thresholds: L = sum(d2 >= D2[j])
  float cc[5];     // Ts exponent coefs
};

// ---------------- K1: img -> C1 (1024^2) + p2 (512^2) -----------------------
__global__ __launch_bounds__(256) void down12_k(const float* __restrict__ img,
                                                float* __restrict__ C1,
                                                float* __restrict__ p2) {
  int X = blockIdx.x * 16 + threadIdx.x;   // 0..511
  int Y = blockIdx.y * 16 + threadIdx.y;   // 0..511
  int c = blockIdx.z;
  const float* ip = img + (size_t)c * HW2048 + (size_t)(4 * Y) * 2048 + 4 * X;
  f4 r0 = __builtin_nontemporal_load((const f4*)(ip));
  f4 r1 = __builtin_nontemporal_load((const f4*)(ip + 2048));
  f4 r2 = __builtin_nontemporal_load((const f4*)(ip + 4096));
  f4 r3 = __builtin_nontemporal_load((const f4*)(ip + 6144));
  float a00 = 0.25f * (r0.x + r0.y + r1.x + r1.y);
  float a01 = 0.25f * (r0.z + r0.w + r1.z + r1.w);
  float a10 = 0.25f * (r2.x + r2.y + r3.x + r3.y);
  float a11 = 0.25f * (r2.z + r2.w + r3.z + r3.w);
  float* cp = C1 + (size_t)c * 1048576 + (size_t)(2 * Y) * 1024 + 2 * X;
  f2 u; u.x = a00; u.y = a01; *(f2*)cp = u;
  f2 v; v.x = a10; v.y = a11; *(f2*)(cp + 1024) = v;
  p2[((size_t)c * 512 + Y) * 512 + X] = 0.25f * (a00 + a01 + a10 + a11);
}

// ---------------- K2: p2 -> p3 + p4 + p5 ------------------------------------
__global__ __launch_bounds__(256) void down345_k(const float* __restrict__ p2,
                                                 float* __restrict__ p3,
                                                 float* __restrict__ p4,
                                                 float* __restrict__ p5) {
  __shared__ float t4[16][17];
  int tx = threadIdx.x, ty = threadIdx.y;          // (16,16); grid (8,8,3)
  int X = blockIdx.x * 16 + tx;
  int Y = blockIdx.y * 16 + ty;
  int c = blockIdx.z;
  const float* ip = p2 + (size_t)c * 262144 + (size_t)(4 * Y) * 512 + 4 * X;
  f4 r0 = *(const f4*)(ip);
  f4 r1 = *(const f4*)(ip + 512);
  f4 r2 = *(const f4*)(ip + 1024);
  f4 r3 = *(const f4*)(ip + 1536);
  float a00 = 0.25f * (r0.x + r0.y + r1.x + r1.y);
  float a01 = 0.25f * (r0.z + r0.w + r1.z + r1.w);
  float a10 = 0.25f * (r2.x + r2.y + r3.x + r3.y);
  float a11 = 0.25f * (r2.z + r2.w + r3.z + r3.w);
  float* cp = p3 + (size_t)c * 65536 + (size_t)(2 * Y) * 256 + 2 * X;
  f2 u; u.x = a00; u.y = a01; *(f2*)cp = u;
  f2 v; v.x = a10; v.y = a11; *(f2*)(cp + 256) = v;
  float m = 0.25f * (a00 + a01 + a10 + a11);
  t4[ty][tx] = m;
  p4[((size_t)c * 128 + Y) * 128 + X] = m;
  __syncthreads();
  int tid = ty * 16 + tx;
  if (tid < 64) {
    int y = tid >> 3, x = tid & 7;
    float w = 0.25f * (t4[2*y][2*x] + t4[2*y][2*x+1] + t4[2*y+1][2*x] + t4[2*y+1][2*x+1]);
    p5[((size_t)c * 64 + blockIdx.y * 8 + y) * 64 + blockIdx.x * 8 + x] = w;
  }
}

// ---------------- helpers ---------------------------------------------------
__device__ __forceinline__ void up_coords(int o, int n, int& i0, int& i1, float& w0) {
  int m = o >> 1;
  if (o & 1) { i0 = m; i1 = min(m + 1, n - 1); w0 = 0.75f; }
  else       { i0 = max(m - 1, 0); i1 = m;     w0 = 0.25f; }
}

__device__ __forceinline__ float calc_B(float dd, int L, const BP& bp) {
  float d = sqrtf(dd);
  float R = 18.75f / (d + 18.75f);
  float R2 = R * R;
  float cL = (L == 1) ? bp.cc[1] : (L == 2) ? bp.cc[2] : (L == 3) ? bp.cc[3] : bp.cc[4];
  float cm = (L == 1) ? bp.cc[0] : (L == 2) ? bp.cc[1] : (L == 3) ? bp.cc[2] : (L == 4) ? bp.cc[3] : bp.cc[4];
  float tsL = (L >= 5) ? 0.f : __expf(-cL * R2);
  float tsm = __expf(-cm * R2);
  return (0.5f - tsL) / (tsm - tsL + 1e-5f);
}

__device__ __forceinline__ void phase_one(const BP& bp, int ph, float w[3]) {
#pragma unroll
  for (int t = 0; t < 3; ++t)
    w[t] = (ph == 0) ? bp.P[0][t] : (ph == 1) ? bp.P[1][t] : (ph == 2) ? bp.P[2][t] : bp.P[3][t];
}

__device__ __forceinline__ float s1px(const float* __restrict__ C1c, int x, int y) {
  int r0, r1, c0, c1; float wy0, wx0;
  up_coords(y, 1024, r0, r1, wy0);
  up_coords(x, 1024, c0, c1, wx0);
  float wy1 = 1.f - wy0, wx1 = 1.f - wx0;
  return wy0 * (wx0 * C1c[(size_t)r0 * 1024 + c0] + wx1 * C1c[(size_t)r0 * 1024 + c1])
       + wy1 * (wx0 * C1c[(size_t)r1 * 1024 + c0] + wx1 * C1c[(size_t)r1 * 1024 + c1]);
}

// ---------------- K3: fused upsample + classify + blend ---------------------
// Block = 128x128 output px of one channel. 512-level pair planes built in LDS.
__global__ __launch_bounds__(256) void fovblend_k(
    const float* __restrict__ img, const float* __restrict__ C1,
    const float* __restrict__ p2, const float* __restrict__ p3,
    const float* __restrict__ p4, const float* __restrict__ p5,
    const float* __restrict__ fixs, int nf, float* __restrict__ out, BP bp) {
  __shared__ float w128[12][13];
  __shared__ float m3[18][19], m4[18][19], m5[18][19];
  __shared__ f2 PW[3][34][35];   // PW0=(p2,u3) PW1=(u3,u4) PW2=(u4,u5)
  __shared__ float sfx[16], sfy[16];

  int bx = blockIdx.x, by = blockIdx.y, ch = blockIdx.z;
  int tid = threadIdx.x;
  int X0p = bx * 128, Y0p = by * 128;
  int r0 = by * 32 - 1, c0 = bx * 32 - 1;     // 512-level window base (34 wide)
  int rb2 = by * 16 - 1, cb2 = bx * 16 - 1;   // 256-level (18 wide)
  int rb1 = by * 8 - 2,  cb1 = bx * 8 - 2;    // 128-level (12 wide)

  const float* imgc = img + (size_t)ch * HW2048;
  const float* C1c  = C1 + (size_t)ch * 1048576;
  const float* p2c  = p2 + (size_t)ch * 262144;
  const float* p3c  = p3 + (size_t)ch * 65536;
  const float* p4c  = p4 + (size_t)ch * 16384;
  const float* p5c  = p5 + (size_t)ch * 4096;

  if (tid < 16) {
    sfx[tid] = (tid < nf) ? fixs[2 * tid]     : 3.0e19f;
    sfy[tid] = (tid < nf) ? fixs[2 * tid + 1] : 3.0e19f;
  }
  int nfc = min(nf, 16);

  // step 1: w128 from p5 (global); prefetch p2 window into registers
  for (int i = tid; i < 144; i += 256) {
    int r = i / 12, c = i - r * 12;
    int y = min(max(rb1 + r, 0), 127), x = min(max(cb1 + c, 0), 127);
    int i0, i1, j0, j1; float wy0, wx0;
    up_coords(y, 64, i0, i1, wy0);
    up_coords(x, 64, j0, j1, wx0);
    float wy1 = 1.f - wy0, wx1 = 1.f - wx0;
    w128[r][c] = wy0 * (wx0 * p5c[i0*64+j0] + wx1 * p5c[i0*64+j1])
               + wy1 * (wx0 * p5c[i1*64+j0] + wx1 * p5c[i1*64+j1]);
  }
  float p2r[5];
#pragma unroll
  for (int k = 0; k < 5; ++k) {
    int i = tid + k * 256;
    if (i < 1156) {
      int r = i / 34, c = i - r * 34;
      int y = min(max(r0 + r, 0), 511), x = min(max(c0 + c, 0), 511);
      p2r[k] = p2c[(size_t)y * 512 + x];
    }
  }
  __syncthreads();

  // step 2: 256-level windows m3 (copy), m4 (up p4), m5 (up w128)
  for (int i = tid; i < 324; i += 256) {
    int r = i / 18, c = i - r * 18;
    int y = min(max(rb2 + r, 0), 255), x = min(max(cb2 + c, 0), 255);
    m3[r][c] = p3c[y * 256 + x];
    int i0, i1, j0, j1; float wy0, wx0;
    up_coords(y, 128, i0, i1, wy0);
    up_coords(x, 128, j0, j1, wx0);
    float wy1 = 1.f - wy0, wx1 = 1.f - wx0;
    m4[r][c] = wy0 * (wx0 * p4c[i0*128+j0] + wx1 * p4c[i0*128+j1])
             + wy1 * (wx0 * p4c[i1*128+j0] + wx1 * p4c[i1*128+j1]);
    int a0 = i0 - rb1, a1 = i1 - rb1, b0 = j0 - cb1, b1 = j1 - cb1;
    m5[r][c] = wy0 * (wx0 * w128[a0][b0] + wx1 * w128[a0][b1])
             + wy1 * (wx0 * w128[a1][b0] + wx1 * w128[a1][b1]);
  }
  __syncthreads();

  // step 3: 512-level pair planes
#pragma unroll
  for (int k = 0; k < 5; ++k) {
    int i = tid + k * 256;
    if (i < 1156) {
      int r = i / 34, c = i - r * 34;
      int y = min(max(r0 + r, 0), 511), x = min(max(c0 + c, 0), 511);
      int i0, i1, j0, j1; float wy0, wx0;
      up_coords(y, 256, i0, i1, wy0);
      up_coords(x, 256, j0, j1, wx0);
      float wy1 = 1.f - wy0, wx1 = 1.f - wx0;
      int a0 = i0 - rb2, a1 = i1 - rb2, b0 = j0 - cb2, b1 = j1 - cb2;
      float u3 = wy0 * (wx0 * m3[a0][b0] + wx1 * m3[a0][b1])
               + wy1 * (wx0 * m3[a1][b0] + wx1 * m3[a1][b1]);
      float u4 = wy0 * (wx0 * m4[a0][b0] + wx1 * m4[a0][b1])
               + wy1 * (wx0 * m4[a1][b0] + wx1 * m4[a1][b1]);
      float u5 = wy0 * (wx0 * m5[a0][b0] + wx1 * m5[a0][b1])
               + wy1 * (wx0 * m5[a1][b0] + wx1 * m5[a1][b1]);
      f2 t;
      t.x = p2r[k]; t.y = u3; PW[0][r][c] = t;
      t.x = u3;     t.y = u4; PW[1][r][c] = t;
      t.x = u4;     t.y = u5; PW[2][r][c] = t;
    }
  }
  __syncthreads();

  // step 4: blend 8 spans (4x2 px) per thread
  int sx = tid & 31, sy8 = tid >> 5;
  for (int it = 0; it < 8; ++it) {
    int sy = sy8 * 8 + it;                       // 0..63
    int x0 = X0p + sx * 4, y0 = Y0p + sy * 2;
    size_t ob = (size_t)ch * HW2048 + (size_t)y0 * 2048 + x0;

    float dd[2][4];
#pragma unroll
    for (int j = 0; j < 2; ++j)
#pragma unroll
      for (int i = 0; i < 4; ++i) dd[j][i] = 3.4e38f;
    for (int f = 0; f < nfc; ++f) {
      float dx0 = (float)x0 - sfx[f], dy0 = (float)y0 - sfy[f];
#pragma unroll
      for (int j = 0; j < 2; ++j) {
        float dy = dy0 + (float)j, dy2 = dy * dy;
#pragma unroll
        for (int i = 0; i < 4; ++i) {
          float dx = dx0 + (float)i;
          dd[j][i] = fminf(dd[j][i], dx * dx + dy2);
        }
      }
    }
    float dmn = dd[0][0], dmx = dd[0][0];
#pragma unroll
    for (int j = 0; j < 2; ++j)
#pragma unroll
      for (int i = 0; i < 4; ++i) {
        dmn = fminf(dmn, dd[j][i]); dmx = fmaxf(dmx, dd[j][i]);
      }
    int lmn = (dmn >= bp.D2[0]) + (dmn >= bp.D2[1]) + (dmn >= bp.D2[2]) +
              (dmn >= bp.D2[3]) + (dmn >= bp.D2[4]);
    int lmx = (dmx >= bp.D2[0]) + (dmx >= bp.D2[1]) + (dmx >= bp.D2[2]) +
              (dmx >= bp.D2[3]) + (dmx >= bp.D2[4]);

    float res[2][4];

    if (lmn == lmx && lmn >= 3) {
      // fast path: whole span one level, both As from one LDS pair plane
      int pl = lmn - 3;
      int wr = sy >> 1, wc = sx;                 // window base rows/cols
      f2 v[3][3];
#pragma unroll
      for (int j = 0; j < 3; ++j) {
        v[j][0] = PW[pl][wr + j][wc];
        v[j][1] = PW[pl][wr + j][wc + 1];
        v[j][2] = PW[pl][wr + j][wc + 2];
      }
      int yph = 2 * (sy & 1);
      const float* wr0 = bp.P[yph];
      const float* wr1 = bp.P[yph + 1];
      f2 rv0[3], rv1[3];
#pragma unroll
      for (int i = 0; i < 3; ++i) {
        rv0[i] = wr0[0] * v[0][i] + wr0[1] * v[1][i] + wr0[2] * v[2][i];
        rv1[i] = wr1[0] * v[0][i] + wr1[1] * v[1][i] + wr1[2] * v[2][i];
      }
#pragma unroll
      for (int p = 0; p < 4; ++p) {
        f2 a0 = bp.P[p][0] * rv0[0] + bp.P[p][1] * rv0[1] + bp.P[p][2] * rv0[2];
        f2 a1 = bp.P[p][0] * rv1[0] + bp.P[p][1] * rv1[1] + bp.P[p][2] * rv1[2];
        float B0 = calc_B(dd[0][p], lmn, bp);
        float B1 = calc_B(dd[1][p], lmn, bp);
        res[0][p] = B0 * a0.x + (1.f - B0) * a0.y;
        res[1][p] = B1 * a1.x + (1.f - B1) * a1.y;
      }
    } else if (lmx == 0) {
      f4 v0 = *(const f4*)(imgc + (size_t)y0 * 2048 + x0);
      f4 v1 = *(const f4*)(imgc + (size_t)(y0 + 1) * 2048 + x0);
      __builtin_nontemporal_store(v0, (f4*)(out + ob));
      __builtin_nontemporal_store(v1, (f4*)(out + ob + 2048));
      continue;
    } else {
      // mixed / fovea span: per-pixel
#pragma unroll
      for (int j = 0; j < 2; ++j)
#pragma unroll
        for (int i = 0; i < 4; ++i) {
          float d = dd[j][i];
          int l = (d >= bp.D2[0]) + (d >= bp.D2[1]) + (d >= bp.D2[2]) +
                  (d >= bp.D2[3]) + (d >= bp.D2[4]);
          int px = x0 + i, py = y0 + j;
          if (l == 0) {
            res[j][i] = imgc[(size_t)py * 2048 + px];
          } else {
            float B = calc_B(d, l, bp);
            float lo, hi;
            if (l >= 2) {
              int pl = (l >= 3) ? l - 3 : 0;
              int lr = (py >> 2) - 32 * by;      // window row of cell-1
              int lc = (px >> 2) - 32 * bx;
              float wrw[3], wcw[3];
              phase_one(bp, py & 3, wrw);
              phase_one(bp, px & 3, wcw);
              f2 acc; acc.x = 0.f; acc.y = 0.f;
#pragma unroll
              for (int jj = 0; jj < 3; ++jj) {
                f2 cs; cs.x = 0.f; cs.y = 0.f;
#pragma unroll
                for (int ii = 0; ii < 3; ++ii)
                  cs += wcw[ii] * PW[pl][lr + jj][lc + ii];
                acc += wrw[jj] * cs;
              }
              if (l >= 3) { lo = acc.x; hi = acc.y; }
              else        { hi = acc.x; lo = s1px(C1c, px, py); }   // l==2
            } else {       // l==1
              hi = s1px(C1c, px, py);
              lo = imgc[(size_t)py * 2048 + px];
            }
            res[j][i] = B * lo + (1.f - B) * hi;
          }
        }
    }

    f4 v0, v1;
    v0.x = res[0][0]; v0.y = res[0][1]; v0.z = res[0][2]; v0.w = res[0][3];
    v1.x = res[1][0]; v1.y = res[1][1]; v1.z = res[1][2]; v1.w = res[1][3];
    __builtin_nontemporal_store(v0, (f4*)(out + ob));
    __builtin_nontemporal_store(v1, (f4*)(out + ob + 2048));
  }
}

extern "C" void kernel_launch(void* const* d_in, const int* in_sizes, int n_in,
                              void* d_out, int out_size, void* d_ws, size_t ws_size,
                              hipStream_t stream) {
  const float* img  = (const float*)d_in[0];
  const float* fixs = (const float*)d_in[1];
  int nf = in_sizes[1] / 2;
  float* out = (float*)d_out;
  float* ws  = (float*)d_ws;

  BP bp;
  const double sig = 0.248, Kd = 3.0, Pd = 7.5, Ad = 2.5;
  double obv = sqrt(log(2.0) / Kd) * sig;
  for (int j = 0; j < 5; ++j) {
    double om = obv * pow(2.0, 2 - j);
    double Dj = Pd * Ad * (1.0 / om - 1.0);
    bp.D2[j] = (float)(Dj * Dj);
  }
  for (int X = 0; X < 5; ++X)
    bp.cc[X] = (float)(Kd * pow(2.0, 2.0 * (X - 2)) / (sig * sig));
  const float Pt[4][3] = {{0.375f, 0.625f, 0.f},
                          {0.1875f, 0.75f, 0.0625f},
                          {0.0625f, 0.75f, 0.1875f},
                          {0.f, 0.625f, 0.375f}};
  for (int a = 0; a < 4; ++a) for (int t = 0; t < 3; ++t) bp.P[a][t] = Pt[a][t];

  size_t o = 0;
  float* C1 = ws + o; o += 3ull * 1024 * 1024;
  float* p2 = ws + o; o += 3ull * 512 * 512;
  float* p3 = ws + o; o += 3ull * 256 * 256;
  float* p4 = ws + o; o += 3ull * 128 * 128;
  float* p5 = ws + o; o += 3ull * 64 * 64;

  down12_k  <<<dim3(32, 32, 3), dim3(16, 16), 0, stream>>>(img, C1, p2);
  down345_k <<<dim3(8, 8, 3),   dim3(16, 16), 0, stream>>>(p2, p3, p4, p5);
  fovblend_k<<<dim3(16, 16, 3), dim3(256),    0, stream>>>(img, C1, p2, p3, p4, p5,
                                                           fixs, nf, out, bp);
}